// Round 1
// 200.327 us; speedup vs baseline: 1.0369x; 1.0369x over previous
//
#include <hip/hip_runtime.h>

#define HIDDEN 768
#define NH 12
#define DH 64
#define BB 4
#define TT 2048
#define MTOT (BB * TT)  // 8192

typedef __bf16 bf16x8 __attribute__((ext_vector_type(8)));
typedef short s16x8 __attribute__((ext_vector_type(8)));
typedef float f32x4 __attribute__((ext_vector_type(4)));

__device__ __forceinline__ unsigned short f2b(float f) {
    unsigned u = __builtin_bit_cast(unsigned, f);
    u += 0x7fffu + ((u >> 16) & 1u);  // RNE
    return (unsigned short)(u >> 16);
}

// pack two f32 -> (bf16(lo)=trunc(a), bf16(hi)=trunc(b)) in one v_perm_b32
__device__ __forceinline__ unsigned pack_bf16(float a, float b) {
    return __builtin_amdgcn_perm(__builtin_bit_cast(unsigned, b),
                                 __builtin_bit_cast(unsigned, a), 0x07060302u);
}

typedef const __attribute__((address_space(1))) unsigned int* gas_ptr;
typedef __attribute__((address_space(3))) unsigned int* las_ptr;
__device__ __forceinline__ void gload16(const void* g, void* l) {
    // DMA: lane i lands at (wave-uniform) lds base + i*16.
    __builtin_amdgcn_global_load_lds((gas_ptr)(uintptr_t)g, (las_ptr)(uintptr_t)l, 16, 0, 0);
}

// ---------------- fused fp32->bf16 for all 5 tensors (1 launch) ----------------
__global__ __launch_bounds__(256) void cvt_all(const float* __restrict__ x,
                                               const float* __restrict__ wq,
                                               const float* __restrict__ wk,
                                               const float* __restrict__ wv,
                                               const float* __restrict__ wo,
                                               unsigned short* __restrict__ out) {
    const size_t NX8 = (size_t)MTOT * HIDDEN / 8;
    const size_t NW8 = (size_t)HIDDEN * HIDDEN / 8;
    size_t i = (size_t)blockIdx.x * 256 + threadIdx.x;
    const float* src;
    size_t off = i;
    float scale = 1.0f;
    if (i < NX8) { src = x; }
    else if (i < NX8 + NW8) { src = wq; off = i - NX8; scale = 0.18033688011112042f; }  // log2e/8
    else if (i < NX8 + 2 * NW8) { src = wk; off = i - NX8 - NW8; }
    else if (i < NX8 + 3 * NW8) { src = wv; off = i - NX8 - 2 * NW8; }
    else { src = wo; off = i - NX8 - 3 * NW8; }
    const float4* p = (const float4*)src + off * 2;
    float4 a = p[0], b = p[1];
    union { uint4 u; unsigned short s[8]; } t;
    t.s[0] = f2b(a.x * scale); t.s[1] = f2b(a.y * scale);
    t.s[2] = f2b(a.z * scale); t.s[3] = f2b(a.w * scale);
    t.s[4] = f2b(b.x * scale); t.s[5] = f2b(b.y * scale);
    t.s[6] = f2b(b.z * scale); t.s[7] = f2b(b.w * scale);
    ((uint4*)out)[i] = t.u;
}

// ---------------- GEMM: C[M,N] = A[M,768] @ B[N,768]^T ----------------
// MROWS x 128 tile, single-buffered m97 2-barrier K-loop, gload16 DMA staging,
// XOR chunk swizzle. MODE 0: bf16 out; 1: fp32 out; 2: bf16 transposed out.
template <int MODE, int MROWS>
__device__ __forceinline__ void gemm_body(const unsigned short* __restrict__ A,
                                          const unsigned short* __restrict__ Bm,
                                          float* __restrict__ Cf,
                                          unsigned short* __restrict__ Cb,
                                          int mBase, int nBase, int N) {
    __shared__ __align__(16) unsigned short Al[MROWS][64];
    __shared__ __align__(16) unsigned short Bl[128][64];
    const int MT = MROWS / 32;  // m-tiles per wave
    const int tid = threadIdx.x;
    const int lane = tid & 63;
    const int wave = tid >> 6;
    const int quad = lane >> 4;
    const int l16 = lane & 15;
    const int mw = (wave >> 1) * (MROWS / 2);
    const int nw = (wave & 1) * 64;
    const int r8 = lane >> 3;
    const int swiz = ((lane & 7) ^ r8) * 8;
    const unsigned short* Asrc = A + (size_t)(mBase + wave * (MROWS / 4) + r8) * HIDDEN + swiz;
    const unsigned short* Bsrc = Bm + (size_t)(nBase + wave * 32 + r8) * HIDDEN + swiz;

    f32x4 acc[MT][4];
#pragma unroll
    for (int mt = 0; mt < MT; ++mt)
#pragma unroll
        for (int nt = 0; nt < 4; ++nt) acc[mt][nt] = (f32x4){0.f, 0.f, 0.f, 0.f};

    for (int kb = 0; kb < HIDDEN / 64; ++kb) {
        if (kb) __syncthreads();  // all waves done reading previous tile
#pragma unroll
        for (int i = 0; i < MROWS / 32; ++i)
            gload16(Asrc + (size_t)i * 8 * HIDDEN + kb * 64,
                    &Al[wave * (MROWS / 4) + i * 8][0]);
#pragma unroll
        for (int j = 0; j < 4; ++j)
            gload16(Bsrc + (size_t)j * 8 * HIDDEN + kb * 64, &Bl[wave * 32 + j * 8][0]);
        __syncthreads();  // staging complete (vmcnt drain)
#pragma unroll
        for (int ks = 0; ks < 2; ++ks) {
            const int cc = ((ks * 4 + quad) ^ (l16 & 7)) * 8;
            bf16x8 af[MT], bf[4];
#pragma unroll
            for (int mt = 0; mt < MT; ++mt)
                af[mt] = *(const bf16x8*)&Al[mw + mt * 16 + l16][cc];
#pragma unroll
            for (int nt = 0; nt < 4; ++nt)
                bf[nt] = *(const bf16x8*)&Bl[nw + nt * 16 + l16][cc];
#pragma unroll
            for (int mt = 0; mt < MT; ++mt)
#pragma unroll
                for (int nt = 0; nt < 4; ++nt)
                    acc[mt][nt] = __builtin_amdgcn_mfma_f32_16x16x32_bf16(
                        af[mt], bf[nt], acc[mt][nt], 0, 0, 0);
        }
    }

#pragma unroll
    for (int mt = 0; mt < MT; ++mt)
#pragma unroll
        for (int nt = 0; nt < 4; ++nt) {
            if (MODE == 2) {
                // transposed pack: 4 consecutive m per lane -> one ushort4
                ushort4 h;
                h.x = f2b(acc[mt][nt][0]); h.y = f2b(acc[mt][nt][1]);
                h.z = f2b(acc[mt][nt][2]); h.w = f2b(acc[mt][nt][3]);
                int m0 = mBase + mw + mt * 16 + quad * 4;
                int col = nBase + nw + nt * 16 + l16;
                *(ushort4*)&Cb[(size_t)col * MTOT + m0] = h;
            } else {
#pragma unroll
                for (int r = 0; r < 4; ++r) {
                    int row = mBase + mw + mt * 16 + quad * 4 + r;
                    int col = nBase + nw + nt * 16 + l16;
                    float v = acc[mt][nt][r];
                    if (MODE == 1)
                        Cf[(size_t)row * N + col] = v;
                    else
                        Cb[(size_t)row * N + col] = f2b(v);
                }
            }
        }
}

// XCD-aware grids (linear id % 8 = XCD): m-tile in blockIdx.x with grid.x a
// multiple of 8 keeps all blocks sharing an A-tile on ONE XCD's L2.
// grid(64, 18): XCD = mtile % 8; the 18 (wsel,nb) blocks of an m-tile co-locate.
__global__ __launch_bounds__(256, 4) void gemm_qkv(const unsigned short* __restrict__ A,
                                                   const unsigned short* __restrict__ W0,
                                                   unsigned short* __restrict__ C0,
                                                   unsigned short* __restrict__ VT) {
    const int wsel = blockIdx.y / 6;
    const int nb = blockIdx.y % 6;
    if (wsel < 2)
        gemm_body<0, 128>(A, W0 + (size_t)wsel * HIDDEN * HIDDEN, nullptr,
                          C0 + (size_t)wsel * MTOT * HIDDEN, blockIdx.x * 128, nb * 128, HIDDEN);
    else
        gemm_body<2, 128>(A, W0 + 2 * (size_t)HIDDEN * HIDDEN, nullptr, VT,
                          blockIdx.x * 128, nb * 128, HIDDEN);
}

// grid(128, 6): XCD = mtile % 8 (128 multiple of 8); ctx-tile reuse per XCD.
__global__ __launch_bounds__(256, 4) void gemm_out(const unsigned short* __restrict__ A,
                                                   const unsigned short* __restrict__ Bm,
                                                   float* __restrict__ Cf) {
    gemm_body<1, 64>(A, Bm, Cf, nullptr, blockIdx.x * 64, blockIdx.y * 128, HIDDEN);
}

// ---------------- Flash attention ----------------
// grid(48, 16): linear id = bh + 48*qt, 48 % 8 == 0 => XCD = bh % 8 — all 16
// q-blocks of one (b,h) share one XCD's L2, so the K/V slice (512 KB) is
// fetched from HBM once per XCD instead of 8x, and steady-state staging hits
// L2 (~200 cy < compute phase => barrier drain stall gone).
//
// R1 changes:
//  * Pl: [4][32][36] (+4-word pad) -> [4][32][32] with 16B-unit XOR swizzle
//    (unit' = unit ^ (row&7)); same 2-way-minimum bank profile, but LDS drops
//    50 KB -> 48 KB (8 KB-granule multiple) => 3 blocks/CU resident instead
//    of 2 (counter: OccupancyPercent 24.7 -> ~37).
//  * __launch_bounds__(256, 3) documents/guards the 3-wave/EU target.
//  * s_setprio(1) around QK^T and PV MFMA clusters (T5; pays once waves on a
//    SIMD are at different phases, which 3-block residency provides).
__global__ __launch_bounds__(256, 3) void attn_kernel(const unsigned short* __restrict__ Qg,
                                                      const unsigned short* __restrict__ Kg,
                                                      const unsigned short* __restrict__ VTg,
                                                      unsigned short* __restrict__ Ctx) {
    __shared__ __align__(16) unsigned short Kl[2][64][64];
    __shared__ __align__(16) unsigned short Vl[2][64][64];
    __shared__ __align__(16) unsigned int Pl[4][32][32];  // [wave][q][64 keys bf16, XOR-swz]
    const int tid = threadIdx.x;
    const int lane = tid & 63;
    const int wave = tid >> 6;
    const int quad = lane >> 4;
    const int l16 = lane & 15;
    const int qt = blockIdx.y;  // 0..15
    const int bh = blockIdx.x;  // 0..47  (XCD = bh % 8)
    const int b = bh / NH, h = bh % NH;
    const int qrow0 = b * TT + qt * 128;
    const int col0 = h * DH;

    const int srow = wave * 16 + (lane >> 3);
    const int swiz = ((lane & 7) ^ (lane >> 3)) * 8;
    const unsigned short* Ksrc = Kg + (size_t)(b * TT + srow) * HIDDEN + col0 + swiz;
    const unsigned short* Vsrc = VTg + (size_t)(col0 + srow) * MTOT + b * TT + swiz;

    auto stage = [&](int buf, int kt) {
#pragma unroll
        for (int i = 0; i < 2; ++i) {
            gload16(Ksrc + (size_t)(kt * 64 + i * 8) * HIDDEN, &Kl[buf][wave * 16 + i * 8][0]);
            gload16(Vsrc + (size_t)(i * 8) * MTOT + kt * 64, &Vl[buf][wave * 16 + i * 8][0]);
        }
    };

    // Q fragments resident all kernel (log2e/8 pre-folded into w_q)
    bf16x8 qf[2][2];
#pragma unroll
    for (int mt = 0; mt < 2; ++mt)
#pragma unroll
        for (int ks = 0; ks < 2; ++ks)
            qf[mt][ks] = *(const bf16x8*)&Qg[(size_t)(qrow0 + wave * 32 + mt * 16 + l16) * HIDDEN +
                                             col0 + ks * 32 + quad * 8];

    s16x8 osv;
#pragma unroll
    for (int e = 0; e < 8; ++e) osv[e] = 0x3F80;  // bf16 1.0
    const bf16x8 ones = __builtin_bit_cast(bf16x8, osv);

    f32x4 o[2][4];
    f32x4 lacc[2];
#pragma unroll
    for (int mt = 0; mt < 2; ++mt) {
        lacc[mt] = (f32x4){0.f, 0.f, 0.f, 0.f};
#pragma unroll
        for (int nt = 0; nt < 4; ++nt) o[mt][nt] = (f32x4){0.f, 0.f, 0.f, 0.f};
    }

    stage(0, 0);
    for (int kt = 0; kt < TT / 64; ++kt) {
        __syncthreads();  // drains only loads issued a full compute phase ago
        if (kt + 1 < TT / 64) stage((kt + 1) & 1, kt + 1);
        const int buf = kt & 1;

        // S^T = K' Q^T : lane holds key = nt*16+quad*4+r, q = mt*16+l16
        f32x4 s[2][4];
#pragma unroll
        for (int mt = 0; mt < 2; ++mt)
#pragma unroll
            for (int nt = 0; nt < 4; ++nt) s[mt][nt] = (f32x4){0.f, 0.f, 0.f, 0.f};
#pragma unroll
        for (int ks = 0; ks < 2; ++ks) {
            const int cc = ((ks * 4 + quad) ^ (l16 & 7)) * 8;
            bf16x8 kf[4];
#pragma unroll
            for (int nt = 0; nt < 4; ++nt)
                kf[nt] = *(const bf16x8*)&Kl[buf][nt * 16 + l16][cc];
            __builtin_amdgcn_s_setprio(1);
#pragma unroll
            for (int mt = 0; mt < 2; ++mt)
#pragma unroll
                for (int nt = 0; nt < 4; ++nt)
                    s[mt][nt] = __builtin_amdgcn_mfma_f32_16x16x32_bf16(kf[nt], qf[mt][ks],
                                                                        s[mt][nt], 0, 0, 0);
            __builtin_amdgcn_s_setprio(0);
        }

        // P = exp2(S), pack 4 consecutive keys -> one ds_write_b64 (XOR-swz unit)
#pragma unroll
        for (int mt = 0; mt < 2; ++mt) {
            const int row = mt * 16 + l16;
            const int rx = l16 & 7;  // row & 7
#pragma unroll
            for (int nt = 0; nt < 4; ++nt) {
                float p0 = __builtin_amdgcn_exp2f(s[mt][nt][0]);
                float p1 = __builtin_amdgcn_exp2f(s[mt][nt][1]);
                float p2 = __builtin_amdgcn_exp2f(s[mt][nt][2]);
                float p3 = __builtin_amdgcn_exp2f(s[mt][nt][3]);
                uint2 w;
                w.x = pack_bf16(p0, p1);
                w.y = pack_bf16(p2, p3);
                const int unit = 2 * nt + (quad >> 1);           // 16B unit within row
                *(uint2*)&Pl[wave][row][(((unit ^ rx) << 2) | ((quad & 1) << 1))] = w;
            }
        }

        // O += P V ; l += P . 1   (same-wave LDS round trip: lgkmcnt only)
#pragma unroll
        for (int ks = 0; ks < 2; ++ks) {
            const int cc = ((ks * 4 + quad) ^ (l16 & 7)) * 8;
            bf16x8 pf[2], vf[4];
#pragma unroll
            for (int mt = 0; mt < 2; ++mt)
                pf[mt] = *(const bf16x8*)((const char*)&Pl[wave][mt * 16 + l16][0] +
                                          ((((ks * 4 + quad) ^ (l16 & 7)) << 4)));
#pragma unroll
            for (int nt = 0; nt < 4; ++nt)
                vf[nt] = *(const bf16x8*)&Vl[buf][nt * 16 + l16][cc];
            __builtin_amdgcn_s_setprio(1);
#pragma unroll
            for (int mt = 0; mt < 2; ++mt)
                lacc[mt] = __builtin_amdgcn_mfma_f32_16x16x32_bf16(pf[mt], ones, lacc[mt], 0, 0, 0);
#pragma unroll
            for (int mt = 0; mt < 2; ++mt)
#pragma unroll
                for (int nt = 0; nt < 4; ++nt)
                    o[mt][nt] = __builtin_amdgcn_mfma_f32_16x16x32_bf16(pf[mt], vf[nt],
                                                                        o[mt][nt], 0, 0, 0);
            __builtin_amdgcn_s_setprio(0);
        }
    }

    // Epilogue: normalize by MFMA row sums (C-layout, no shuffles)
#pragma unroll
    for (int mt = 0; mt < 2; ++mt)
#pragma unroll
        for (int r = 0; r < 4; ++r) {
            float inv = __builtin_amdgcn_rcpf(lacc[mt][r]);
            int row = qrow0 + wave * 32 + mt * 16 + quad * 4 + r;
#pragma unroll
            for (int nt = 0; nt < 4; ++nt)
                Ctx[(size_t)row * HIDDEN + col0 + nt * 16 + l16] = f2b(o[mt][nt][r] * inv);
        }
}

// ---------------- launch ----------------
extern "C" void kernel_launch(void* const* d_in, const int* in_sizes, int n_in,
                              void* d_out, int out_size, void* d_ws, size_t ws_size,
                              hipStream_t stream) {
    const float* x = (const float*)d_in[0];
    const float* wq = (const float*)d_in[1];
    const float* wk = (const float*)d_in[2];
    const float* wv = (const float*)d_in[3];
    const float* wo = (const float*)d_in[4];
    float* out = (float*)d_out;

    const size_t NX = (size_t)MTOT * HIDDEN;
    const size_t NW = (size_t)HIDDEN * HIDDEN;
    unsigned short* ws = (unsigned short*)d_ws;
    unsigned short* xb = ws;            // cvt_all writes x|wq|wk|wv|wo contiguously
    unsigned short* wqb = xb + NX;
    unsigned short* wob = wqb + 3 * NW;
    unsigned short* qb = wob + NW;      // q|k contiguous (fused GEMM output)
    unsigned short* kb = qb + NX;
    unsigned short* cb = kb + NX;       // ctx
    unsigned short* vtb = cb + NX;      // V^T written directly by gemm_qkv

    cvt_all<<<(int)((NX + 4 * NW) / 8 / 256), 256, 0, stream>>>(x, wq, wk, wv, wo, xb);

    gemm_qkv<<<dim3(MTOT / 128, 18), 256, 0, stream>>>(xb, wqb, qb, vtb);

    attn_kernel<<<dim3(BB * NH, TT / 128), 256, 0, stream>>>(qb, kb, vtb, cb);

    gemm_out<<<dim3(MTOT / 64, 6), 256, 0, stream>>>(cb, wob, out);
}

// Round 2
// 195.736 us; speedup vs baseline: 1.0612x; 1.0235x over previous
//
#include <hip/hip_runtime.h>

#define HIDDEN 768
#define NH 12
#define DH 64
#define BB 4
#define TT 2048
#define MTOT (BB * TT)  // 8192

typedef __bf16 bf16x8 __attribute__((ext_vector_type(8)));
typedef short s16x8 __attribute__((ext_vector_type(8)));
typedef float f32x4 __attribute__((ext_vector_type(4)));

__device__ __forceinline__ unsigned short f2b(float f) {
    unsigned u = __builtin_bit_cast(unsigned, f);
    u += 0x7fffu + ((u >> 16) & 1u);  // RNE
    return (unsigned short)(u >> 16);
}

// pack two f32 -> (bf16(lo)=trunc(a), bf16(hi)=trunc(b)) in one v_perm_b32
__device__ __forceinline__ unsigned pack_bf16(float a, float b) {
    return __builtin_amdgcn_perm(__builtin_bit_cast(unsigned, b),
                                 __builtin_bit_cast(unsigned, a), 0x07060302u);
}

typedef const __attribute__((address_space(1))) unsigned int* gas_ptr;
typedef __attribute__((address_space(3))) unsigned int* las_ptr;
__device__ __forceinline__ void gload16(const void* g, void* l) {
    // DMA: lane i lands at (wave-uniform) lds base + i*16.
    __builtin_amdgcn_global_load_lds((gas_ptr)(uintptr_t)g, (las_ptr)(uintptr_t)l, 16, 0, 0);
}

// ---------------- fused fp32->bf16 for all 5 tensors (1 launch) ----------------
__global__ __launch_bounds__(256) void cvt_all(const float* __restrict__ x,
                                               const float* __restrict__ wq,
                                               const float* __restrict__ wk,
                                               const float* __restrict__ wv,
                                               const float* __restrict__ wo,
                                               unsigned short* __restrict__ out) {
    const size_t NX8 = (size_t)MTOT * HIDDEN / 8;
    const size_t NW8 = (size_t)HIDDEN * HIDDEN / 8;
    size_t i = (size_t)blockIdx.x * 256 + threadIdx.x;
    const float* src;
    size_t off = i;
    float scale = 1.0f;
    if (i < NX8) { src = x; }
    else if (i < NX8 + NW8) { src = wq; off = i - NX8; scale = 0.18033688011112042f; }  // log2e/8
    else if (i < NX8 + 2 * NW8) { src = wk; off = i - NX8 - NW8; }
    else if (i < NX8 + 3 * NW8) { src = wv; off = i - NX8 - 2 * NW8; }
    else { src = wo; off = i - NX8 - 3 * NW8; }
    const float4* p = (const float4*)src + off * 2;
    float4 a = p[0], b = p[1];
    union { uint4 u; unsigned short s[8]; } t;
    t.s[0] = f2b(a.x * scale); t.s[1] = f2b(a.y * scale);
    t.s[2] = f2b(a.z * scale); t.s[3] = f2b(a.w * scale);
    t.s[4] = f2b(b.x * scale); t.s[5] = f2b(b.y * scale);
    t.s[6] = f2b(b.z * scale); t.s[7] = f2b(b.w * scale);
    ((uint4*)out)[i] = t.u;
}

// ---------------- GEMM: C[M,N] = A[M,768] @ B[N,768]^T ----------------
// MROWS x 128 tile, single-buffered m97 2-barrier K-loop, gload16 DMA staging,
// XOR chunk swizzle. MODE 0: bf16 out; 1: fp32 out; 2: bf16 transposed out.
template <int MODE, int MROWS>
__device__ __forceinline__ void gemm_body(const unsigned short* __restrict__ A,
                                          const unsigned short* __restrict__ Bm,
                                          float* __restrict__ Cf,
                                          unsigned short* __restrict__ Cb,
                                          int mBase, int nBase, int N) {
    __shared__ __align__(16) unsigned short Al[MROWS][64];
    __shared__ __align__(16) unsigned short Bl[128][64];
    const int MT = MROWS / 32;  // m-tiles per wave
    const int tid = threadIdx.x;
    const int lane = tid & 63;
    const int wave = tid >> 6;
    const int quad = lane >> 4;
    const int l16 = lane & 15;
    const int mw = (wave >> 1) * (MROWS / 2);
    const int nw = (wave & 1) * 64;
    const int r8 = lane >> 3;
    const int swiz = ((lane & 7) ^ r8) * 8;
    const unsigned short* Asrc = A + (size_t)(mBase + wave * (MROWS / 4) + r8) * HIDDEN + swiz;
    const unsigned short* Bsrc = Bm + (size_t)(nBase + wave * 32 + r8) * HIDDEN + swiz;

    f32x4 acc[MT][4];
#pragma unroll
    for (int mt = 0; mt < MT; ++mt)
#pragma unroll
        for (int nt = 0; nt < 4; ++nt) acc[mt][nt] = (f32x4){0.f, 0.f, 0.f, 0.f};

    for (int kb = 0; kb < HIDDEN / 64; ++kb) {
        if (kb) __syncthreads();  // all waves done reading previous tile
#pragma unroll
        for (int i = 0; i < MROWS / 32; ++i)
            gload16(Asrc + (size_t)i * 8 * HIDDEN + kb * 64,
                    &Al[wave * (MROWS / 4) + i * 8][0]);
#pragma unroll
        for (int j = 0; j < 4; ++j)
            gload16(Bsrc + (size_t)j * 8 * HIDDEN + kb * 64, &Bl[wave * 32 + j * 8][0]);
        __syncthreads();  // staging complete (vmcnt drain)
#pragma unroll
        for (int ks = 0; ks < 2; ++ks) {
            const int cc = ((ks * 4 + quad) ^ (l16 & 7)) * 8;
            bf16x8 af[MT], bf[4];
#pragma unroll
            for (int mt = 0; mt < MT; ++mt)
                af[mt] = *(const bf16x8*)&Al[mw + mt * 16 + l16][cc];
#pragma unroll
            for (int nt = 0; nt < 4; ++nt)
                bf[nt] = *(const bf16x8*)&Bl[nw + nt * 16 + l16][cc];
#pragma unroll
            for (int mt = 0; mt < MT; ++mt)
#pragma unroll
                for (int nt = 0; nt < 4; ++nt)
                    acc[mt][nt] = __builtin_amdgcn_mfma_f32_16x16x32_bf16(
                        af[mt], bf[nt], acc[mt][nt], 0, 0, 0);
        }
    }

#pragma unroll
    for (int mt = 0; mt < MT; ++mt)
#pragma unroll
        for (int nt = 0; nt < 4; ++nt) {
            if (MODE == 2) {
                // transposed pack: 4 consecutive m per lane -> one ushort4
                ushort4 h;
                h.x = f2b(acc[mt][nt][0]); h.y = f2b(acc[mt][nt][1]);
                h.z = f2b(acc[mt][nt][2]); h.w = f2b(acc[mt][nt][3]);
                int m0 = mBase + mw + mt * 16 + quad * 4;
                int col = nBase + nw + nt * 16 + l16;
                *(ushort4*)&Cb[(size_t)col * MTOT + m0] = h;
            } else {
#pragma unroll
                for (int r = 0; r < 4; ++r) {
                    int row = mBase + mw + mt * 16 + quad * 4 + r;
                    int col = nBase + nw + nt * 16 + l16;
                    float v = acc[mt][nt][r];
                    if (MODE == 1)
                        Cf[(size_t)row * N + col] = v;
                    else
                        Cb[(size_t)row * N + col] = f2b(v);
                }
            }
        }
}

// XCD-aware grids (linear id % 8 = XCD): m-tile in blockIdx.x with grid.x a
// multiple of 8 keeps all blocks sharing an A-tile on ONE XCD's L2.
// grid(64, 18): XCD = mtile % 8; the 18 (wsel,nb) blocks of an m-tile co-locate.
__global__ __launch_bounds__(256, 4) void gemm_qkv(const unsigned short* __restrict__ A,
                                                   const unsigned short* __restrict__ W0,
                                                   unsigned short* __restrict__ C0,
                                                   unsigned short* __restrict__ VT) {
    const int wsel = blockIdx.y / 6;
    const int nb = blockIdx.y % 6;
    if (wsel < 2)
        gemm_body<0, 128>(A, W0 + (size_t)wsel * HIDDEN * HIDDEN, nullptr,
                          C0 + (size_t)wsel * MTOT * HIDDEN, blockIdx.x * 128, nb * 128, HIDDEN);
    else
        gemm_body<2, 128>(A, W0 + 2 * (size_t)HIDDEN * HIDDEN, nullptr, VT,
                          blockIdx.x * 128, nb * 128, HIDDEN);
}

// grid(128, 6): XCD = mtile % 8 (128 multiple of 8); ctx-tile reuse per XCD.
__global__ __launch_bounds__(256, 4) void gemm_out(const unsigned short* __restrict__ A,
                                                   const unsigned short* __restrict__ Bm,
                                                   float* __restrict__ Cf) {
    gemm_body<1, 64>(A, Bm, Cf, nullptr, blockIdx.x * 64, blockIdx.y * 128, HIDDEN);
}

// ---------------- Flash attention ----------------
// grid(48, 16): XCD = bh % 8 — all 16 q-blocks of one (b,h) share one XCD's L2.
//
// R2: ks-granular softmax/PV pipeline. Old chain per kt:
//   QK -> 32 exp2 -> 8 Pl writes -> lgkm turnaround -> PV(ks0,ks1)
// New chain:
//   QK -> exp2 keys 0-31 -> write -> PV ks0  (exp2 keys 32-63 issue on the
//   VALU/trans pipe while PV-ks0 MFMAs drain the matrix pipe) -> write -> PV ks1
// Cuts one exposed LDS write->read turnaround and creates in-wave MFMA||VALU
// overlap. All Pl/Kl/Vl swizzle formulas identical to R1 (verified).
__global__ __launch_bounds__(256, 3) void attn_kernel(const unsigned short* __restrict__ Qg,
                                                      const unsigned short* __restrict__ Kg,
                                                      const unsigned short* __restrict__ VTg,
                                                      unsigned short* __restrict__ Ctx) {
    __shared__ __align__(16) unsigned short Kl[2][64][64];
    __shared__ __align__(16) unsigned short Vl[2][64][64];
    __shared__ __align__(16) unsigned int Pl[4][32][32];  // [wave][q][64 keys bf16, XOR-swz]
    const int tid = threadIdx.x;
    const int lane = tid & 63;
    const int wave = tid >> 6;
    const int quad = lane >> 4;
    const int l16 = lane & 15;
    const int qt = blockIdx.y;  // 0..15
    const int bh = blockIdx.x;  // 0..47  (XCD = bh % 8)
    const int b = bh / NH, h = bh % NH;
    const int qrow0 = b * TT + qt * 128;
    const int col0 = h * DH;

    const int srow = wave * 16 + (lane >> 3);
    const int swiz = ((lane & 7) ^ (lane >> 3)) * 8;
    const unsigned short* Ksrc = Kg + (size_t)(b * TT + srow) * HIDDEN + col0 + swiz;
    const unsigned short* Vsrc = VTg + (size_t)(col0 + srow) * MTOT + b * TT + swiz;

    auto stage = [&](int buf, int kt) {
#pragma unroll
        for (int i = 0; i < 2; ++i) {
            gload16(Ksrc + (size_t)(kt * 64 + i * 8) * HIDDEN, &Kl[buf][wave * 16 + i * 8][0]);
            gload16(Vsrc + (size_t)(i * 8) * MTOT + kt * 64, &Vl[buf][wave * 16 + i * 8][0]);
        }
    };

    // Q fragments resident all kernel (log2e/8 pre-folded into w_q)
    bf16x8 qf[2][2];
#pragma unroll
    for (int mt = 0; mt < 2; ++mt)
#pragma unroll
        for (int ks = 0; ks < 2; ++ks)
            qf[mt][ks] = *(const bf16x8*)&Qg[(size_t)(qrow0 + wave * 32 + mt * 16 + l16) * HIDDEN +
                                             col0 + ks * 32 + quad * 8];

    s16x8 osv;
#pragma unroll
    for (int e = 0; e < 8; ++e) osv[e] = 0x3F80;  // bf16 1.0
    const bf16x8 ones = __builtin_bit_cast(bf16x8, osv);

    f32x4 o[2][4];
    f32x4 lacc[2];
#pragma unroll
    for (int mt = 0; mt < 2; ++mt) {
        lacc[mt] = (f32x4){0.f, 0.f, 0.f, 0.f};
#pragma unroll
        for (int nt = 0; nt < 4; ++nt) o[mt][nt] = (f32x4){0.f, 0.f, 0.f, 0.f};
    }

    const int rx = l16 & 7;

    stage(0, 0);
    for (int kt = 0; kt < TT / 64; ++kt) {
        __syncthreads();  // drains only loads issued a full compute phase ago
        if (kt + 1 < TT / 64) stage((kt + 1) & 1, kt + 1);
        const int buf = kt & 1;

        // S^T = K' Q^T : lane holds key = nt*16+quad*4+r, q = mt*16+l16
        f32x4 s[2][4];
#pragma unroll
        for (int mt = 0; mt < 2; ++mt)
#pragma unroll
            for (int nt = 0; nt < 4; ++nt) s[mt][nt] = (f32x4){0.f, 0.f, 0.f, 0.f};
#pragma unroll
        for (int ks = 0; ks < 2; ++ks) {
            const int cc = ((ks * 4 + quad) ^ rx) * 8;
            bf16x8 kf[4];
#pragma unroll
            for (int nt = 0; nt < 4; ++nt)
                kf[nt] = *(const bf16x8*)&Kl[buf][nt * 16 + l16][cc];
            __builtin_amdgcn_s_setprio(1);
#pragma unroll
            for (int mt = 0; mt < 2; ++mt)
#pragma unroll
                for (int nt = 0; nt < 4; ++nt)
                    s[mt][nt] = __builtin_amdgcn_mfma_f32_16x16x32_bf16(kf[nt], qf[mt][ks],
                                                                        s[mt][nt], 0, 0, 0);
            __builtin_amdgcn_s_setprio(0);
        }

        // ---- ks-granular softmax/PV pipeline ----
#pragma unroll
        for (int ks = 0; ks < 2; ++ks) {
            // P = exp2(S) for keys [ks*32, ks*32+32); pack; write (XOR-swz unit)
#pragma unroll
            for (int mt = 0; mt < 2; ++mt) {
                const int row = mt * 16 + l16;
#pragma unroll
                for (int nt2 = 0; nt2 < 2; ++nt2) {
                    const int nt = ks * 2 + nt2;
                    float p0 = __builtin_amdgcn_exp2f(s[mt][nt][0]);
                    float p1 = __builtin_amdgcn_exp2f(s[mt][nt][1]);
                    float p2 = __builtin_amdgcn_exp2f(s[mt][nt][2]);
                    float p3 = __builtin_amdgcn_exp2f(s[mt][nt][3]);
                    uint2 w;
                    w.x = pack_bf16(p0, p1);
                    w.y = pack_bf16(p2, p3);
                    const int unit = 2 * nt + (quad >> 1);  // 16B unit within row
                    *(uint2*)&Pl[wave][row][(((unit ^ rx) << 2) | ((quad & 1) << 1))] = w;
                }
            }

            // O += P V ; l += P . 1   (LDS FIFO: reads follow this ks's writes)
            const int cc = ((ks * 4 + quad) ^ rx) * 8;
            bf16x8 pf[2], vf[4];
#pragma unroll
            for (int nt = 0; nt < 4; ++nt)
                vf[nt] = *(const bf16x8*)&Vl[buf][nt * 16 + l16][cc];
#pragma unroll
            for (int mt = 0; mt < 2; ++mt)
                pf[mt] = *(const bf16x8*)((const char*)&Pl[wave][mt * 16 + l16][0] +
                                          ((((ks * 4 + quad) ^ rx) << 4)));
            __builtin_amdgcn_s_setprio(1);
#pragma unroll
            for (int mt = 0; mt < 2; ++mt)
                lacc[mt] = __builtin_amdgcn_mfma_f32_16x16x32_bf16(pf[mt], ones, lacc[mt], 0, 0, 0);
#pragma unroll
            for (int mt = 0; mt < 2; ++mt)
#pragma unroll
                for (int nt = 0; nt < 4; ++nt)
                    o[mt][nt] = __builtin_amdgcn_mfma_f32_16x16x32_bf16(pf[mt], vf[nt],
                                                                        o[mt][nt], 0, 0, 0);
            __builtin_amdgcn_s_setprio(0);
        }
    }

    // Epilogue: normalize by MFMA row sums (C-layout, no shuffles)
#pragma unroll
    for (int mt = 0; mt < 2; ++mt)
#pragma unroll
        for (int r = 0; r < 4; ++r) {
            float inv = __builtin_amdgcn_rcpf(lacc[mt][r]);
            int row = qrow0 + wave * 32 + mt * 16 + quad * 4 + r;
#pragma unroll
            for (int nt = 0; nt < 4; ++nt)
                Ctx[(size_t)row * HIDDEN + col0 + nt * 16 + l16] = f2b(o[mt][nt][r] * inv);
        }
}

// ---------------- launch ----------------
extern "C" void kernel_launch(void* const* d_in, const int* in_sizes, int n_in,
                              void* d_out, int out_size, void* d_ws, size_t ws_size,
                              hipStream_t stream) {
    const float* x = (const float*)d_in[0];
    const float* wq = (const float*)d_in[1];
    const float* wk = (const float*)d_in[2];
    const float* wv = (const float*)d_in[3];
    const float* wo = (const float*)d_in[4];
    float* out = (float*)d_out;

    const size_t NX = (size_t)MTOT * HIDDEN;
    const size_t NW = (size_t)HIDDEN * HIDDEN;
    unsigned short* ws = (unsigned short*)d_ws;
    unsigned short* xb = ws;            // cvt_all writes x|wq|wk|wv|wo contiguously
    unsigned short* wqb = xb + NX;
    unsigned short* wob = wqb + 3 * NW;
    unsigned short* qb = wob + NW;      // q|k contiguous (fused GEMM output)
    unsigned short* kb = qb + NX;
    unsigned short* cb = kb + NX;       // ctx
    unsigned short* vtb = cb + NX;      // V^T written directly by gemm_qkv

    cvt_all<<<(int)((NX + 4 * NW) / 8 / 256), 256, 0, stream>>>(x, wq, wk, wv, wo, xb);

    gemm_qkv<<<dim3(MTOT / 128, 18), 256, 0, stream>>>(xb, wqb, qb, vtb);

    attn_kernel<<<dim3(BB * NH, TT / 128), 256, 0, stream>>>(qb, kb, vtb, cb);

    gemm_out<<<dim3(MTOT / 64, 6), 256, 0, stream>>>(cb, wob, out);
}